// Round 1
// baseline (490.720 us; speedup 1.0000x reference)
//
#include <hip/hip_runtime.h>
#include <stdint.h>
#include <stddef.h>

// Problem constants
#define BB 4
#define CC 256
#define NH 8
#define DH 32
#define NN 2304      // 48*48
#define O3 768
#define HID 256
#define QK_SCALE 0.17677669529663687f  // 32^-0.5

typedef __attribute__((ext_vector_type(8))) short short8;
typedef __attribute__((ext_vector_type(4))) float float4v;

__device__ __forceinline__ unsigned short f2bf(float f) {
    union { float f; uint32_t u; } v; v.f = f;
    uint32_t u = v.u;
    return (unsigned short)((u + 0x7FFFu + ((u >> 16) & 1u)) >> 16);   // RNE
}

// ---------------------------------------------------------------------------
// K0: cast w_out -> bf16
// ---------------------------------------------------------------------------
__global__ void cast_bf16_kernel(const float* __restrict__ src,
                                 unsigned short* __restrict__ dst, int n) {
    int i = blockIdx.x * 256 + threadIdx.x;
    if (i < n) dst[i] = f2bf(src[i]);
}

// ---------------------------------------------------------------------------
// K1: QKV projection, fp32 tiled GEMM.  qkv[b][o][n] = sum_c w[o][c] x[b][c][n]
// grid (O3/64, NN/64, BB), block 256. 64x64 tile, 4x4 micro-tile, k-step 16.
// ---------------------------------------------------------------------------
__global__ __launch_bounds__(256) void qkv_gemm(const float* __restrict__ x,
                                                const float* __restrict__ wqkv,
                                                float* __restrict__ qkv) {
    const int o0 = blockIdx.x * 64;
    const int n0 = blockIdx.y * 64;
    const int b  = blockIdx.z;
    __shared__ float As[16][68];  // As[k][o]
    __shared__ float Bs[16][68];  // Bs[k][n]
    const int t  = threadIdx.x;
    const int tx = t & 15, ty = t >> 4;
    float acc[4][4] = {};
    const float* xb = x + (size_t)b * CC * NN;

    for (int c0 = 0; c0 < CC; c0 += 16) {
        {   // w tile [64 o][16 c] -> As[k][o] (transpose in LDS)
            int row = t >> 2;           // 0..63  (o)
            int cc  = (t & 3) * 4;      // 0,4,8,12
            float4 w4 = *(const float4*)(wqkv + (size_t)(o0 + row) * CC + c0 + cc);
            As[cc + 0][row] = w4.x; As[cc + 1][row] = w4.y;
            As[cc + 2][row] = w4.z; As[cc + 3][row] = w4.w;
        }
        {   // x tile [16 c][64 n] -> Bs[k][n]
            int row = t >> 4;           // 0..15  (c)
            int cc  = (t & 15) * 4;     // 0..60
            float4 x4 = *(const float4*)(xb + (size_t)(c0 + row) * NN + n0 + cc);
            *(float4*)&Bs[row][cc] = x4;
        }
        __syncthreads();
        #pragma unroll
        for (int k = 0; k < 16; ++k) {
            float a[4], bv[4];
            *(float4*)a  = *(const float4*)&As[k][ty * 4];
            *(float4*)bv = *(const float4*)&Bs[k][tx * 4];
            #pragma unroll
            for (int i = 0; i < 4; ++i)
                #pragma unroll
                for (int j = 0; j < 4; ++j)
                    acc[i][j] = fmaf(a[i], bv[j], acc[i][j]);
        }
        __syncthreads();
    }
    float* outp = qkv + (size_t)b * O3 * NN;
    #pragma unroll
    for (int i = 0; i < 4; ++i) {
        int o = o0 + ty * 4 + i;
        *(float4*)(outp + (size_t)o * NN + n0 + tx * 4) = *(float4*)acc[i];
    }
}

// ---------------------------------------------------------------------------
// K2: pack qkv fp32 [b][768][n] into:
//   q bf16 [b][h][n][32] (scaled), k bf16 [b][h][n][32], v bf16 [b][h][32][n]
// grid (O3/32, NN/64, BB), block 256; tile = [32 o][64 n]
// ---------------------------------------------------------------------------
__global__ __launch_bounds__(256) void pack_qkv(const float* __restrict__ qkv,
                                                unsigned short* __restrict__ q,
                                                unsigned short* __restrict__ k,
                                                unsigned short* __restrict__ v) {
    const int og = blockIdx.x;          // 0..23
    const int o0 = og * 32;
    const int n0 = blockIdx.y * 64;
    const int b  = blockIdx.z;
    const int which = o0 >> 8;          // 0=q 1=k 2=v
    const int h = (o0 >> 5) & 7;
    const float* src = qkv + ((size_t)b * O3 + o0) * NN + n0;
    const int t = threadIdx.x;

    if (which == 2) {                   // v: layout matches, cast only
        unsigned short* dst = v + (((size_t)b * NH + h) * DH) * NN + n0;
        #pragma unroll
        for (int r = 0; r < 8; ++r) {
            int idx = t + r * 256;
            int d = idx >> 6, i = idx & 63;
            dst[(size_t)d * NN + i] = f2bf(src[(size_t)d * NN + i]);
        }
    } else {                            // q/k: transpose [32 d][64 n] -> [n][d]
        __shared__ float ls[32][65];
        #pragma unroll
        for (int r = 0; r < 8; ++r) {
            int idx = t + r * 256;
            int d = idx >> 6, i = idx & 63;
            ls[d][i] = src[(size_t)d * NN + i];
        }
        __syncthreads();
        const float scale = (which == 0) ? QK_SCALE : 1.0f;
        unsigned short* dst = (which == 0 ? q : k) + (((size_t)b * NH + h) * NN + n0) * DH;
        #pragma unroll
        for (int r = 0; r < 8; ++r) {
            int idx = t + r * 256;
            int i = idx >> 5, d = idx & 31;
            dst[(size_t)i * DH + d] = f2bf(ls[d][i] * scale);
        }
    }
}

// ---------------------------------------------------------------------------
// K3: fused flash attention.
// grid (NN/16, NH), block 256 = 4 waves; wave w = batch w, rows i0..i0+15.
// Bias tile [16 i][64 j] staged in LDS once per j-step, shared by all 4
// batches -> bias HBM traffic = 170 MB exactly.
// MFMA layouts (guide-verified): A[m=lane&15][k=quad*8+j];
// B[k=quad*8+j][n=lane&15]; C/D col=lane&15, row=quad*4+reg.
// ---------------------------------------------------------------------------
__global__ __launch_bounds__(256) void attn_kernel(const unsigned short* __restrict__ qg,
                                                   const unsigned short* __restrict__ kg,
                                                   const unsigned short* __restrict__ vg,
                                                   const float* __restrict__ bias,
                                                   unsigned short* __restrict__ ao) {
    const int i0   = blockIdx.x * 16;
    const int h    = blockIdx.y;
    const int t    = threadIdx.x;
    const int w    = t >> 6;            // wave id == batch
    const int lane = t & 63;
    const int l15  = lane & 15;
    const int quad = lane >> 4;

    __shared__ float bs[16][68];               // bias tile
    __shared__ unsigned short ps[4][16][72];   // P per wave, padded (+8) rows

    const size_t bh = (size_t)w * NH + h;
    const unsigned short* qp = qg + bh * NN * DH;
    const unsigned short* kp = kg + bh * NN * DH;
    const unsigned short* vp = vg + bh * DH * NN;

    // Q A-fragment, held for the whole kernel
    short8 qf = *(const short8*)(qp + (size_t)(i0 + l15) * DH + quad * 8);

    float4v o0acc = {0.f, 0.f, 0.f, 0.f};
    float4v o1acc = {0.f, 0.f, 0.f, 0.f};
    float4v zero  = {0.f, 0.f, 0.f, 0.f};
    float m_r[4], l_r[4];
    #pragma unroll
    for (int r = 0; r < 4; ++r) { m_r[r] = -1e30f; l_r[r] = 0.f; }

    const float* biasrow = bias + ((size_t)h * NN + i0) * NN;

    for (int jt = 0; jt < NN; jt += 64) {
        {   // cooperative bias tile load: 16 rows x 64 cols fp32
            int row = t >> 4;
            int col = (t & 15) * 4;
            float4 b4 = *(const float4*)(biasrow + (size_t)row * NN + jt + col);
            bs[row][col] = b4.x; bs[row][col + 1] = b4.y;
            bs[row][col + 2] = b4.z; bs[row][col + 3] = b4.w;
        }
        __syncthreads();

        // S = Q K^T  (one MFMA per 16j group, K-dim = d = 32)
        float4v s[4];
        #pragma unroll
        for (int jj = 0; jj < 4; ++jj) {
            short8 kf = *(const short8*)(kp + (size_t)(jt + jj * 16 + l15) * DH + quad * 8);
            s[jj] = __builtin_amdgcn_mfma_f32_16x16x32_bf16(qf, kf, zero, 0, 0, 0);
        }

        // bias add + online softmax (row r lives at C/D row quad*4+r)
        #pragma unroll
        for (int r = 0; r < 4; ++r) {
            int row = quad * 4 + r;
            float v0 = s[0][r] + bs[row][l15];
            float v1 = s[1][r] + bs[row][l15 + 16];
            float v2 = s[2][r] + bs[row][l15 + 32];
            float v3 = s[3][r] + bs[row][l15 + 48];
            float mx = fmaxf(fmaxf(v0, v1), fmaxf(v2, v3));
            #pragma unroll
            for (int off = 1; off < 16; off <<= 1)
                mx = fmaxf(mx, __shfl_xor(mx, off, 64));
            float mnew  = fmaxf(m_r[r], mx);
            float alpha = __expf(m_r[r] - mnew);
            float p0 = __expf(v0 - mnew), p1 = __expf(v1 - mnew);
            float p2 = __expf(v2 - mnew), p3 = __expf(v3 - mnew);
            float rs = p0 + p1 + p2 + p3;
            #pragma unroll
            for (int off = 1; off < 16; off <<= 1)
                rs += __shfl_xor(rs, off, 64);
            l_r[r] = l_r[r] * alpha + rs;
            m_r[r] = mnew;
            o0acc[r] *= alpha;
            o1acc[r] *= alpha;
            ps[w][row][l15]      = f2bf(p0);
            ps[w][row][l15 + 16] = f2bf(p1);
            ps[w][row][l15 + 32] = f2bf(p2);
            ps[w][row][l15 + 48] = f2bf(p3);
        }
        __syncthreads();

        // P (A-layout via LDS) x V (B-frags from global [d][n])
        short8 pa0 = *(const short8*)&ps[w][l15][quad * 8];
        short8 pa1 = *(const short8*)&ps[w][l15][32 + quad * 8];
        short8 vf00 = *(const short8*)(vp + (size_t)l15 * NN        + jt + quad * 8);
        short8 vf01 = *(const short8*)(vp + (size_t)l15 * NN        + jt + 32 + quad * 8);
        short8 vf10 = *(const short8*)(vp + (size_t)(l15 + 16) * NN + jt + quad * 8);
        short8 vf11 = *(const short8*)(vp + (size_t)(l15 + 16) * NN + jt + 32 + quad * 8);
        o0acc = __builtin_amdgcn_mfma_f32_16x16x32_bf16(pa0, vf00, o0acc, 0, 0, 0);
        o0acc = __builtin_amdgcn_mfma_f32_16x16x32_bf16(pa1, vf01, o0acc, 0, 0, 0);
        o1acc = __builtin_amdgcn_mfma_f32_16x16x32_bf16(pa0, vf10, o1acc, 0, 0, 0);
        o1acc = __builtin_amdgcn_mfma_f32_16x16x32_bf16(pa1, vf11, o1acc, 0, 0, 0);
        __syncthreads();   // protect bs/ps for next iteration
    }

    // epilogue: normalize, write bf16 to ao[b][i][h*32+d]
    unsigned short* aop = ao + ((size_t)w * NN + i0) * HID + h * DH;
    #pragma unroll
    for (int r = 0; r < 4; ++r) {
        int row = quad * 4 + r;
        float inv = 1.0f / l_r[r];
        aop[(size_t)row * HID + l15]      = f2bf(o0acc[r] * inv);
        aop[(size_t)row * HID + 16 + l15] = f2bf(o1acc[r] * inv);
    }
}

// ---------------------------------------------------------------------------
// K4: out projection, bf16 MFMA.
// out[b][o][n] = sum_c w_out[o][c] * ao[b][n][c] + b_out[o]
// grid (NN/64, HID/64, BB), block 256 (4 waves); wave w: o rows o0+16w..+15
// ---------------------------------------------------------------------------
__global__ __launch_bounds__(256) void out_proj(const unsigned short* __restrict__ wob,
                                                const unsigned short* __restrict__ aob,
                                                const float* __restrict__ bout,
                                                float* __restrict__ out) {
    const int n0 = blockIdx.x * 64;
    const int o0 = blockIdx.y * 64;
    const int b  = blockIdx.z;
    const int t = threadIdx.x;
    const int w = t >> 6, lane = t & 63, l15 = lane & 15, quad = lane >> 4;
    const int orow = o0 + w * 16;

    float4v acc[4] = {{0.f,0.f,0.f,0.f},{0.f,0.f,0.f,0.f},
                      {0.f,0.f,0.f,0.f},{0.f,0.f,0.f,0.f}};
    const unsigned short* ap = aob + ((size_t)b * NN + n0) * HID;
    #pragma unroll
    for (int c0 = 0; c0 < HID; c0 += 32) {
        short8 af = *(const short8*)(wob + (size_t)(orow + l15) * HID + c0 + quad * 8);
        #pragma unroll
        for (int jj = 0; jj < 4; ++jj) {
            short8 bf = *(const short8*)(ap + (size_t)(jj * 16 + l15) * HID + c0 + quad * 8);
            acc[jj] = __builtin_amdgcn_mfma_f32_16x16x32_bf16(af, bf, acc[jj], 0, 0, 0);
        }
    }
    float* op = out + (size_t)b * HID * NN;
    #pragma unroll
    for (int r = 0; r < 4; ++r) {
        int o = orow + quad * 4 + r;
        float bv = bout[o];
        #pragma unroll
        for (int jj = 0; jj < 4; ++jj)
            op[(size_t)o * NN + n0 + jj * 16 + l15] = acc[jj][r] + bv;
    }
}

// ---------------------------------------------------------------------------
extern "C" void kernel_launch(void* const* d_in, const int* in_sizes, int n_in,
                              void* d_out, int out_size, void* d_ws, size_t ws_size,
                              hipStream_t stream) {
    const float* x        = (const float*)d_in[0];  // [4][256][2304]
    const float* pos_bias = (const float*)d_in[1];  // [8][2304][2304]
    const float* w_qkv    = (const float*)d_in[2];  // [768][256]
    const float* w_out    = (const float*)d_in[3];  // [256][256]
    const float* b_out    = (const float*)d_in[4];  // [256]
    float* out = (float*)d_out;                     // [4][256][2304]

    // workspace carve-up (all offsets 256B-aligned); total ~45.2 MB
    char* ws = (char*)d_ws;
    float*          qkv = (float*)(ws);                               // 28,311,552 B
    unsigned short* q   = (unsigned short*)(ws + 28311552);           //  4,718,592 B
    unsigned short* k   = (unsigned short*)(ws + 33030144);           //  4,718,592 B
    unsigned short* v   = (unsigned short*)(ws + 37748736);           //  4,718,592 B
    unsigned short* ao  = (unsigned short*)(ws + 42467328);           //  4,718,592 B
    unsigned short* wob = (unsigned short*)(ws + 47185920);           //    131,072 B

    cast_bf16_kernel<<<(HID * HID + 255) / 256, 256, 0, stream>>>(w_out, wob, HID * HID);
    qkv_gemm<<<dim3(O3 / 64, NN / 64, BB), 256, 0, stream>>>(x, w_qkv, qkv);
    pack_qkv<<<dim3(O3 / 32, NN / 64, BB), 256, 0, stream>>>(qkv, q, k, v);
    attn_kernel<<<dim3(NN / 16, NH), 256, 0, stream>>>(q, k, v, pos_bias, ao);
    out_proj<<<dim3(NN / 64, HID / 64, BB), 256, 0, stream>>>(wob, ao, b_out, out);
}

// Round 2
// 474.402 us; speedup vs baseline: 1.0344x; 1.0344x over previous
//
#include <hip/hip_runtime.h>
#include <stdint.h>
#include <stddef.h>

// Problem constants
#define BB 4
#define CC 256
#define NH 8
#define DH 32
#define NN 2304      // 48*48
#define O3 768
#define HID 256
#define QK_SCALE 0.17677669529663687f  // 32^-0.5

typedef __attribute__((ext_vector_type(8))) short short8;
typedef __attribute__((ext_vector_type(4))) float float4v;

__device__ __forceinline__ unsigned short f2bf(float f) {
    union { float f; uint32_t u; } v; v.f = f;
    uint32_t u = v.u;
    return (unsigned short)((u + 0x7FFFu + ((u >> 16) & 1u)) >> 16);   // RNE
}
__device__ __forceinline__ float bf2f(unsigned short s) {
    union { uint32_t u; float f; } v; v.u = ((uint32_t)s) << 16;
    return v.f;
}

// ---------------------------------------------------------------------------
// K0: cast weights. w_qkv -> bf16 hi + lo (error-free split vs single bf16),
// w_out -> bf16. grid 768 x 256 covers 196608 = |w_qkv|; first 65536 also
// handle w_out.
// ---------------------------------------------------------------------------
__global__ void cast_weights(const float* __restrict__ wqkv,
                             const float* __restrict__ wout,
                             unsigned short* __restrict__ whi,
                             unsigned short* __restrict__ wlo,
                             unsigned short* __restrict__ wob) {
    int i = blockIdx.x * 256 + threadIdx.x;
    float wv = wqkv[i];
    unsigned short hi = f2bf(wv);
    whi[i] = hi;
    wlo[i] = f2bf(wv - bf2f(hi));
    if (i < HID * HID) wob[i] = f2bf(wout[i]);
}

// ---------------------------------------------------------------------------
// K1: transpose-cast x [b][c][n] fp32 -> xT [b][n][c] bf16.
// grid (NN/32, CC/32, BB), block 256, 32x32 tiles through LDS.
// ---------------------------------------------------------------------------
__global__ __launch_bounds__(256) void transpose_x(const float* __restrict__ x,
                                                   unsigned short* __restrict__ xT) {
    const int n0 = blockIdx.x * 32, c0 = blockIdx.y * 32, b = blockIdx.z;
    __shared__ float ls[32][33];
    const int t = threadIdx.x;
    {
        int c = t >> 3, nc = (t & 7) * 4;
        float4 v4 = *(const float4*)(x + ((size_t)b * CC + c0 + c) * NN + n0 + nc);
        ls[c][nc] = v4.x; ls[c][nc + 1] = v4.y; ls[c][nc + 2] = v4.z; ls[c][nc + 3] = v4.w;
    }
    __syncthreads();
    {
        int n = t >> 3, cl = (t & 7) * 4;
        uint32_t p0 = (uint32_t)f2bf(ls[cl + 0][n]) | ((uint32_t)f2bf(ls[cl + 1][n]) << 16);
        uint32_t p1 = (uint32_t)f2bf(ls[cl + 2][n]) | ((uint32_t)f2bf(ls[cl + 3][n]) << 16);
        uint32_t* dst = (uint32_t*)(xT + ((size_t)b * NN + n0 + n) * CC + c0 + cl);
        dst[0] = p0; dst[1] = p1;
    }
}

// ---------------------------------------------------------------------------
// K2: fused QKV projection, bf16 MFMA, writes q/k/v directly in final layouts.
//   q,k bf16 [b][h][n][32] (q scaled), v bf16 [b][h][32][n]
// grid (12, NN/64, BB), block 256 (4 waves).
//  blockIdx.x < 8  : "qk" mode, C = X^T(n x c) * W^T(c x o), o in [0,512)
//  blockIdx.x >= 8 : "v"  mode, C = W(o x c) * X(c x n),    o in [512,768)
// w is split hi+lo: two MFMAs per fragment pair -> w rounding error ~0.
// ---------------------------------------------------------------------------
__global__ __launch_bounds__(256) void qkv_gemm_bf16(const unsigned short* __restrict__ xT,
                                                     const unsigned short* __restrict__ whi,
                                                     const unsigned short* __restrict__ wlo,
                                                     unsigned short* __restrict__ q,
                                                     unsigned short* __restrict__ k,
                                                     unsigned short* __restrict__ v) {
    const int og = blockIdx.x;
    const int n0 = blockIdx.y * 64;
    const int b  = blockIdx.z;
    const int t = threadIdx.x;
    const int w = t >> 6, lane = t & 63, l15 = lane & 15, quad = lane >> 4;
    const unsigned short* xb = xT + (size_t)b * NN * CC;

    float4v acc[4] = {{0.f,0.f,0.f,0.f},{0.f,0.f,0.f,0.f},
                      {0.f,0.f,0.f,0.f},{0.f,0.f,0.f,0.f}};

    if (og < 8) {   // ---- qk mode: A = xT rows n, B = w rows o ----
        const int o0 = og * 64;
        const unsigned short* ap = xb + (size_t)(n0 + w * 16 + l15) * CC + quad * 8;
        #pragma unroll
        for (int c0 = 0; c0 < CC; c0 += 32) {
            short8 af = *(const short8*)(ap + c0);
            #pragma unroll
            for (int jj = 0; jj < 4; ++jj) {
                const size_t wo = (size_t)(o0 + jj * 16 + l15) * CC + c0 + quad * 8;
                short8 bh = *(const short8*)(whi + wo);
                short8 bl = *(const short8*)(wlo + wo);
                acc[jj] = __builtin_amdgcn_mfma_f32_16x16x32_bf16(af, bh, acc[jj], 0, 0, 0);
                acc[jj] = __builtin_amdgcn_mfma_f32_16x16x32_bf16(af, bl, acc[jj], 0, 0, 0);
            }
        }
        // C: row = n = n0+16w+quad*4+r, col = o = o0+jj*16+l15
        #pragma unroll
        for (int jj = 0; jj < 4; ++jj) {
            const int o = o0 + jj * 16 + l15;
            const int which = o >> 8;            // 0=q 1=k
            const int h = (o >> 5) & 7, d = o & 31;
            unsigned short* dst = which ? k : q;
            const float sc = which ? 1.0f : QK_SCALE;
            #pragma unroll
            for (int r = 0; r < 4; ++r) {
                const int n = n0 + w * 16 + quad * 4 + r;
                dst[(((size_t)b * NH + h) * NN + n) * DH + d] = f2bf(acc[jj][r] * sc);
            }
        }
    } else {        // ---- v mode: A = w rows o, B = xT rows n ----
        const int o0 = 512 + (og - 8) * 64;
        const size_t wr = (size_t)(o0 + w * 16 + l15) * CC + quad * 8;
        #pragma unroll
        for (int c0 = 0; c0 < CC; c0 += 32) {
            short8 ah = *(const short8*)(whi + wr + c0);
            short8 al = *(const short8*)(wlo + wr + c0);
            #pragma unroll
            for (int jj = 0; jj < 4; ++jj) {
                short8 bf = *(const short8*)(xb + (size_t)(n0 + jj * 16 + l15) * CC + c0 + quad * 8);
                acc[jj] = __builtin_amdgcn_mfma_f32_16x16x32_bf16(ah, bf, acc[jj], 0, 0, 0);
                acc[jj] = __builtin_amdgcn_mfma_f32_16x16x32_bf16(al, bf, acc[jj], 0, 0, 0);
            }
        }
        // C: row = o = o0+16w+quad*4+r, col = n = n0+jj*16+l15
        #pragma unroll
        for (int r = 0; r < 4; ++r) {
            const int o = o0 + w * 16 + quad * 4 + r;
            const int h = (o >> 5) & 7, d = o & 31;
            #pragma unroll
            for (int jj = 0; jj < 4; ++jj) {
                const int n = n0 + jj * 16 + l15;
                v[(((size_t)b * NH + h) * DH + d) * NN + n] = f2bf(acc[jj][r]);
            }
        }
    }
}

// ---------------------------------------------------------------------------
// K3: fused flash attention, restructured.
// grid (NN/16, NH), block 256 = 4 waves; wave w = batch w, rows i0..i0+15.
// j-tile 128. ONE barrier per iteration: ps is wave-private (same-wave DS ops
// are in-order, no block barrier needed); bias tile is double-buffered with a
// register prefetch so the HBM latency overlaps a full iteration of compute.
// ---------------------------------------------------------------------------
__global__ __launch_bounds__(256) void attn_kernel(const unsigned short* __restrict__ qg,
                                                   const unsigned short* __restrict__ kg,
                                                   const unsigned short* __restrict__ vg,
                                                   const float* __restrict__ bias,
                                                   unsigned short* __restrict__ ao) {
    const int i0   = blockIdx.x * 16;
    const int h    = blockIdx.y;
    const int t    = threadIdx.x;
    const int w    = t >> 6;            // wave id == batch
    const int lane = t & 63;
    const int l15  = lane & 15;
    const int quad = lane >> 4;

    __shared__ float bs[2][16][132];             // 16.9 KB bias double-buffer
    __shared__ unsigned short ps[4][16][136];    // 17.4 KB P, per-wave private

    const size_t bh = (size_t)w * NH + h;
    const unsigned short* qp = qg + bh * NN * DH;
    const unsigned short* kp = kg + bh * NN * DH;
    const unsigned short* vp = vg + bh * DH * NN;

    short8 qf = *(const short8*)(qp + (size_t)(i0 + l15) * DH + quad * 8);

    float4v oa0 = {0.f, 0.f, 0.f, 0.f};
    float4v oa1 = {0.f, 0.f, 0.f, 0.f};
    float4v zero = {0.f, 0.f, 0.f, 0.f};
    float m_r[4], l_r[4];
    #pragma unroll
    for (int r = 0; r < 4; ++r) { m_r[r] = -1e30f; l_r[r] = 0.f; }

    const float* bp = bias + ((size_t)h * NN + i0) * NN;
    const int brow = t >> 4;            // 0..15
    const int bcol = (t & 15) * 8;      // 0..120

    {   // preload tile 0
        const float* src = bp + (size_t)brow * NN + bcol;
        float4 f0 = *(const float4*)src;
        float4 f1 = *(const float4*)(src + 4);
        *(float4*)&bs[0][brow][bcol]     = f0;
        *(float4*)&bs[0][brow][bcol + 4] = f1;
    }
    __syncthreads();

    for (int it = 0; it < NN / 128; ++it) {
        const int jt  = it * 128;
        const int buf = it & 1;
        const bool pre = (it + 1 < NN / 128);
        float4 nf0, nf1;
        if (pre) {   // prefetch next bias tile into registers
            const float* src = bp + (size_t)brow * NN + jt + 128 + bcol;
            nf0 = *(const float4*)src;
            nf1 = *(const float4*)(src + 4);
        }

        // S = Q K^T : 8 MFMAs over the 128-j tile
        float4v s[8];
        #pragma unroll
        for (int jj = 0; jj < 8; ++jj) {
            short8 kf = *(const short8*)(kp + (size_t)(jt + jj * 16 + l15) * DH + quad * 8);
            s[jj] = __builtin_amdgcn_mfma_f32_16x16x32_bf16(qf, kf, zero, 0, 0, 0);
        }

        // bias add + online softmax (C/D row = quad*4+r, col = l15 + 16*jj)
        #pragma unroll
        for (int r = 0; r < 4; ++r) {
            const int row = quad * 4 + r;
            float vv[8];
            #pragma unroll
            for (int jj = 0; jj < 8; ++jj)
                vv[jj] = s[jj][r] + bs[buf][row][jj * 16 + l15];
            float mx = vv[0];
            #pragma unroll
            for (int jj = 1; jj < 8; ++jj) mx = fmaxf(mx, vv[jj]);
            #pragma unroll
            for (int off = 1; off < 16; off <<= 1)
                mx = fmaxf(mx, __shfl_xor(mx, off, 64));
            const float mnew  = fmaxf(m_r[r], mx);
            const float alpha = __expf(m_r[r] - mnew);
            float rs = 0.f;
            #pragma unroll
            for (int jj = 0; jj < 8; ++jj) {
                float p = __expf(vv[jj] - mnew);
                rs += p;
                ps[w][row][jj * 16 + l15] = f2bf(p);
            }
            #pragma unroll
            for (int off = 1; off < 16; off <<= 1)
                rs += __shfl_xor(rs, off, 64);
            l_r[r] = l_r[r] * alpha + rs;
            m_r[r] = mnew;
            oa0[r] *= alpha;
            oa1[r] *= alpha;
        }

        // O += P x V  (ps is wave-private: same-wave DS ordering, no barrier)
        #pragma unroll
        for (int c = 0; c < 4; ++c) {
            short8 pa = *(const short8*)&ps[w][l15][c * 32 + quad * 8];
            short8 v0 = *(const short8*)(vp + (size_t)l15 * NN        + jt + c * 32 + quad * 8);
            short8 v1 = *(const short8*)(vp + (size_t)(l15 + 16) * NN + jt + c * 32 + quad * 8);
            oa0 = __builtin_amdgcn_mfma_f32_16x16x32_bf16(pa, v0, oa0, 0, 0, 0);
            oa1 = __builtin_amdgcn_mfma_f32_16x16x32_bf16(pa, v1, oa1, 0, 0, 0);
        }

        if (pre) {   // commit prefetched bias to the other buffer
            *(float4*)&bs[buf ^ 1][brow][bcol]     = nf0;
            *(float4*)&bs[buf ^ 1][brow][bcol + 4] = nf1;
        }
        __syncthreads();   // the ONLY barrier: protects both bias buffers
    }

    // epilogue: normalize, write bf16 to ao[b][i][h*32+d]
    unsigned short* aop = ao + ((size_t)w * NN + i0) * HID + h * DH;
    #pragma unroll
    for (int r = 0; r < 4; ++r) {
        const int row = quad * 4 + r;
        const float inv = 1.0f / l_r[r];
        aop[(size_t)row * HID + l15]      = f2bf(oa0[r] * inv);
        aop[(size_t)row * HID + 16 + l15] = f2bf(oa1[r] * inv);
    }
}

// ---------------------------------------------------------------------------
// K4: out projection, bf16 MFMA.
// out[b][o][n] = sum_c w_out[o][c] * ao[b][n][c] + b_out[o]
// grid (NN/64, HID/64, BB), block 256 (4 waves); wave w: o rows o0+16w..+15
// ---------------------------------------------------------------------------
__global__ __launch_bounds__(256) void out_proj(const unsigned short* __restrict__ wob,
                                                const unsigned short* __restrict__ aob,
                                                const float* __restrict__ bout,
                                                float* __restrict__ out) {
    const int n0 = blockIdx.x * 64;
    const int o0 = blockIdx.y * 64;
    const int b  = blockIdx.z;
    const int t = threadIdx.x;
    const int w = t >> 6, lane = t & 63, l15 = lane & 15, quad = lane >> 4;
    const int orow = o0 + w * 16;

    float4v acc[4] = {{0.f,0.f,0.f,0.f},{0.f,0.f,0.f,0.f},
                      {0.f,0.f,0.f,0.f},{0.f,0.f,0.f,0.f}};
    const unsigned short* ap = aob + ((size_t)b * NN + n0) * HID;
    #pragma unroll
    for (int c0 = 0; c0 < HID; c0 += 32) {
        short8 af = *(const short8*)(wob + (size_t)(orow + l15) * HID + c0 + quad * 8);
        #pragma unroll
        for (int jj = 0; jj < 4; ++jj) {
            short8 bf = *(const short8*)(ap + (size_t)(jj * 16 + l15) * HID + c0 + quad * 8);
            acc[jj] = __builtin_amdgcn_mfma_f32_16x16x32_bf16(af, bf, acc[jj], 0, 0, 0);
        }
    }
    float* op = out + (size_t)b * HID * NN;
    #pragma unroll
    for (int r = 0; r < 4; ++r) {
        const int o = orow + quad * 4 + r;
        const float bv = bout[o];
        #pragma unroll
        for (int jj = 0; jj < 4; ++jj)
            op[(size_t)o * NN + n0 + jj * 16 + l15] = acc[jj][r] + bv;
    }
}

// ---------------------------------------------------------------------------
extern "C" void kernel_launch(void* const* d_in, const int* in_sizes, int n_in,
                              void* d_out, int out_size, void* d_ws, size_t ws_size,
                              hipStream_t stream) {
    const float* x        = (const float*)d_in[0];  // [4][256][2304]
    const float* pos_bias = (const float*)d_in[1];  // [8][2304][2304]
    const float* w_qkv    = (const float*)d_in[2];  // [768][256]
    const float* w_out    = (const float*)d_in[3];  // [256][256]
    const float* b_out    = (const float*)d_in[4];  // [256]
    float* out = (float*)d_out;                     // [4][256][2304]

    // workspace carve-up (256B-aligned); total ~24.5 MB
    char* ws = (char*)d_ws;
    unsigned short* xT  = (unsigned short*)(ws);                      // 4,718,592 B
    unsigned short* q   = (unsigned short*)(ws + 4718592);            // 4,718,592 B
    unsigned short* k   = (unsigned short*)(ws + 9437184);            // 4,718,592 B
    unsigned short* v   = (unsigned short*)(ws + 14155776);           // 4,718,592 B
    unsigned short* ao  = (unsigned short*)(ws + 18874368);           // 4,718,592 B
    unsigned short* wob = (unsigned short*)(ws + 23592960);           //   131,072 B
    unsigned short* whi = (unsigned short*)(ws + 23724032);           //   393,216 B
    unsigned short* wlo = (unsigned short*)(ws + 24117248);           //   393,216 B

    cast_weights<<<O3 * CC / 256, 256, 0, stream>>>(w_qkv, w_out, whi, wlo, wob);
    transpose_x<<<dim3(NN / 32, CC / 32, BB), 256, 0, stream>>>(x, xT);
    qkv_gemm_bf16<<<dim3(12, NN / 64, BB), 256, 0, stream>>>(xT, whi, wlo, q, k, v);
    attn_kernel<<<dim3(NN / 16, NH), 256, 0, stream>>>(q, k, v, pos_bias, ao);
    out_proj<<<dim3(NN / 64, HID / 64, BB), 256, 0, stream>>>(wob, ao, b_out, out);
}